// Round 2
// baseline (1737.387 us; speedup 1.0000x reference)
//
#include <hip/hip_runtime.h>

// Problem constants
#define BB   2
#define HH   256
#define WW   256
#define HWSZ (HH * WW)        // 65536
#define CC   24
#define KSZ  7
#define KK   49               // 7*7
#define CKK  1176             // 24*49
#define PADK 3

// ---------------------------------------------------------------------------
// Kernel 1: depth_latent = Conv2d(1, 24, 3, pad=1)(depth)
// one thread per pixel; 24 channels in registers; coalesced stores per channel
// ---------------------------------------------------------------------------
__global__ __launch_bounds__(256) void k_latent(
    const float* __restrict__ depth, const float* __restrict__ w_dp,
    const float* __restrict__ b_dp, float* __restrict__ latent) {
  int t = blockIdx.x * 256 + threadIdx.x;       // 0 .. B*HW-1
  int b = t / HWSZ, p = t % HWSZ;
  int y = p / WW, x = p % WW;
  const float* dp = depth + (size_t)b * HWSZ;
  float patch[9];
#pragma unroll
  for (int dy = 0; dy < 3; ++dy)
#pragma unroll
    for (int dx = 0; dx < 3; ++dx) {
      int yy = y + dy - 1, xx = x + dx - 1;
      bool ok = (yy >= 0 && yy < HH && xx >= 0 && xx < WW);
      patch[dy * 3 + dx] = ok ? dp[yy * WW + xx] : 0.f;
    }
#pragma unroll
  for (int c = 0; c < CC; ++c) {
    float acc = b_dp[c];
#pragma unroll
    for (int i = 0; i < 9; ++i) acc = fmaf(w_dp[c * 9 + i], patch[i], acc);
    latent[((size_t)b * CC + c) * HWSZ + p] = acc;
  }
}

// ---------------------------------------------------------------------------
// Kernel 2: one diffusion iteration with ON-THE-FLY kernel prediction.
// Per pixel p: logit[c,kk] = b_kp[c*49+kk] + sum_27 w_kp * tex_patch
//              e = exp(logit); z = sum e
//              acc[c] = sum_kk e * src_norm[c, y+i-3, x+j-3]
// src_norm = src * srcz (srcz = 1/Z of previous iteration; nullptr = 1).
// Non-final: dst[c,p] = acc[c] (UNNORMALIZED), zout[p] = 1/z.
// Final:     out[p] = (sum_c w_td[c]*acc[c]) / z + b_td.
// Conv weights are read with wave-uniform addresses -> scalar loads (s_load),
// broadcast for free into v_fma. LDS holds only the src halo tile + tex tile.
// ---------------------------------------------------------------------------
template <bool FINAL>
__global__ __launch_bounds__(256) void k_diffuse_rc(
    const float* __restrict__ src, const float* __restrict__ srcz,
    const float* __restrict__ tex, const float* __restrict__ w_kp,
    const float* __restrict__ b_kp, float* __restrict__ dst,
    float* __restrict__ zout, const float* __restrict__ w_td,
    const float* __restrict__ b_td) {
  __shared__ float ls[CC * 484];   // 24 ch x 22x22 src halo (46.5 KB)
  __shared__ float lt[3 * 324];    // 3 ch x 18x18 texture halo (3.9 KB)
  int b = blockIdx.z;
  int x0 = blockIdx.x * 16, y0 = blockIdx.y * 16;
  int tx = threadIdx.x, ty = threadIdx.y;
  int tid = ty * 16 + tx;

  // stage src halo tile, folding in previous iteration's 1/Z
  for (int idx = tid; idx < 484; idx += 256) {
    int iy = idx / 22, ix = idx % 22;
    int yy = y0 + iy - PADK, xx = x0 + ix - PADK;
    bool ok = (yy >= 0 && yy < HH && xx >= 0 && xx < WW);
    int gp = yy * WW + xx;
    float s = (ok && srcz) ? srcz[b * HWSZ + gp] : 1.f;
#pragma unroll
    for (int c = 0; c < CC; ++c)
      ls[c * 484 + idx] = ok ? src[((size_t)b * CC + c) * HWSZ + gp] * s : 0.f;
  }
  // stage texture halo tile (for the 3x3 conv)
  for (int idx = tid; idx < 972; idx += 256) {
    int ci = idx / 324, r = idx % 324;
    int iy = r / 18, ix = r % 18;
    int yy = y0 + iy - 1, xx = x0 + ix - 1;
    bool ok = (yy >= 0 && yy < HH && xx >= 0 && xx < WW);
    lt[idx] = ok ? tex[((size_t)b * 3 + ci) * HWSZ + yy * WW + xx] : 0.f;
  }
  __syncthreads();

  // per-thread 3x3x3 texture patch in registers
  float patch[27];
#pragma unroll
  for (int ci = 0; ci < 3; ++ci)
#pragma unroll
    for (int dy = 0; dy < 3; ++dy)
#pragma unroll
      for (int dx = 0; dx < 3; ++dx)
        patch[ci * 9 + dy * 3 + dx] = lt[ci * 324 + (ty + dy) * 18 + (tx + dx)];

  int p = (y0 + ty) * WW + (x0 + tx);
  float z = 0.f, res = 0.f;
  for (int c = 0; c < CC; ++c) {
    const float* lsc = ls + c * 484 + ty * 22 + tx;
    const float* wrow = w_kp + (size_t)c * KK * 27;   // uniform -> s_load
    const float* brow = b_kp + c * KK;                // uniform -> s_load
    float accc = 0.f;
#pragma unroll
    for (int i = 0; i < KSZ; ++i)
#pragma unroll
      for (int j = 0; j < KSZ; ++j) {
        const int kk = i * KSZ + j;
        float logit = brow[kk];
        const float* w = wrow + kk * 27;
#pragma unroll
        for (int m = 0; m < 27; ++m) logit = fmaf(w[m], patch[m], logit);
        float e = __expf(logit);
        z += e;
        accc = fmaf(e, lsc[i * 22 + j], accc);
      }
    if (FINAL) res = fmaf(w_td[c], accc, res);
    else dst[((size_t)b * CC + c) * HWSZ + p] = accc;
  }
  float rz = 1.f / z;
  if (FINAL) dst[(size_t)b * HWSZ + p] = fmaf(res, rz, b_td[0]);
  else zout[b * HWSZ + p] = rz;
}

// ---------------------------------------------------------------------------
extern "C" void kernel_launch(void* const* d_in, const int* in_sizes, int n_in,
                              void* d_out, int out_size, void* d_ws, size_t ws_size,
                              hipStream_t stream) {
  const float* depth = (const float*)d_in[0];
  const float* tex   = (const float*)d_in[1];
  const float* w_dp  = (const float*)d_in[2];
  const float* b_dp  = (const float*)d_in[3];
  const float* w_kp  = (const float*)d_in[4];
  const float* b_kp  = (const float*)d_in[5];
  const float* w_td  = (const float*)d_in[6];
  const float* b_td  = (const float*)d_in[7];
  float* out = (float*)d_out;

  // workspace carve-up: 2x 12.58 MB ping-pong + 2x 0.5 MB z — 25 MiB total
  char* ws = (char*)d_ws;
  const size_t buf_elems = (size_t)BB * CC * HWSZ;       // 3,145,728 floats
  float* bufA = (float*)ws;                              // latent / ping
  float* bufB = (float*)(ws + buf_elems * 4);            // pong
  float* zA   = (float*)(ws + 2 * buf_elems * 4);
  float* zB   = (float*)(ws + 2 * buf_elems * 4 + (size_t)BB * HWSZ * 4);

  // Phase 1: depth_latent -> bufA
  k_latent<<<dim3(BB * HWSZ / 256), dim3(256), 0, stream>>>(depth, w_dp, b_dp, bufA);

  // Phase 2: 4 diffusion iterations, kernels recomputed on the fly.
  // Unnormalized ping-pong; 1/Z folded into next iteration's staging.
  dim3 grid(WW / 16, HH / 16, BB), blk(16, 16);
  k_diffuse_rc<false><<<grid, blk, 0, stream>>>(bufA, nullptr, tex, w_kp, b_kp, bufB, zA, w_td, b_td);
  k_diffuse_rc<false><<<grid, blk, 0, stream>>>(bufB, zA,      tex, w_kp, b_kp, bufA, zB, w_td, b_td);
  k_diffuse_rc<false><<<grid, blk, 0, stream>>>(bufA, zB,      tex, w_kp, b_kp, bufB, zA, w_td, b_td);
  k_diffuse_rc<true ><<<grid, blk, 0, stream>>>(bufB, zA,      tex, w_kp, b_kp, out,  nullptr, w_td, b_td);
}

// Round 3
// 718.006 us; speedup vs baseline: 2.4197x; 2.4197x over previous
//
#include <hip/hip_runtime.h>

// Problem constants
#define BB   2
#define HH   256
#define WW   256
#define HWSZ (HH * WW)        // 65536
#define CC   24
#define KSZ  7
#define KK   49               // 7*7
#define PADK 3
#define G    8                // channel groups
#define CPG  3                // channels per group (24/8)
// LDS src halo tile: 22 rows x stride 24 (pad 22->24: max 2-way bank alias = free)
#define LSTR 24

// ---------------------------------------------------------------------------
// One diffusion iteration for a 16x16 tile and a 3-channel group, with
// ON-THE-FLY kernel prediction:
//   logit[c,kk] = b_kp[c*49+kk] + sum_27 w_kp*tex_patch   (uniform s_load wts)
//   e = exp(logit);  acc[c] = sum_kk e * src_norm[c, ...]
// z is texture-only -> iteration-invariant: FIRST computes group-partial z,
// k_zred reduces to invZ once, iters 2..4 just consume it (folded into the
// halo staging multiply). Outputs stay UNNORMALIZED between iterations.
// FIRST also fuses depth_latent = Conv2d(1,24,3,pad=1) into halo staging.
// FINAL writes per-group partial of sum_c w_td[c]*acc[c]; k_final combines.
// ---------------------------------------------------------------------------
template <bool FIRST, bool FINAL>
__global__ __launch_bounds__(256, 8) void k_diffuse_g(
    const float* __restrict__ depth, const float* __restrict__ src,
    const float* __restrict__ invZ, const float* __restrict__ tex,
    const float* __restrict__ w_dp, const float* __restrict__ b_dp,
    const float* __restrict__ w_kp, const float* __restrict__ b_kp,
    float* __restrict__ dst, float* __restrict__ part,
    const float* __restrict__ w_td) {
  __shared__ float ls[CPG * 22 * LSTR];  // 3ch x 22x22 src halo, stride 24 (6.3 KB)
  __shared__ float lt[3 * 324];          // 3ch x 18x18 texture halo (3.9 KB)
  __shared__ float ld[576];              // 24x24 depth halo (FIRST only, 2.3 KB)

  int b = blockIdx.z / G, g = blockIdx.z % G, c0 = g * CPG;
  int x0 = blockIdx.x * 16, y0 = blockIdx.y * 16;
  int tx = threadIdx.x, ty = threadIdx.y;
  int tid = ty * 16 + tx;

  // stage texture halo (18x18, for the 3x3 kernel-predictor conv)
  for (int idx = tid; idx < 972; idx += 256) {
    int ci = idx / 324, r = idx % 324;
    int iy = r / 18, ix = r % 18;
    int yy = y0 + iy - 1, xx = x0 + ix - 1;
    bool ok = (yy >= 0 && yy < HH && xx >= 0 && xx < WW);
    lt[idx] = ok ? tex[((size_t)b * 3 + ci) * HWSZ + yy * WW + xx] : 0.f;
  }
  if (FIRST) {
    // depth halo 24x24 at (y0-4, x0-4): src-halo 22x22 + 3x3-conv ring
    for (int idx = tid; idx < 576; idx += 256) {
      int iy = idx / 24, ix = idx % 24;
      int yy = y0 + iy - 4, xx = x0 + ix - 4;
      bool ok = (yy >= 0 && yy < HH && xx >= 0 && xx < WW);
      ld[idx] = ok ? depth[(size_t)b * HWSZ + yy * WW + xx] : 0.f;
    }
  }
  __syncthreads();

  // stage src halo (22x22 at (y0-3, x0-3)), normalized by previous invZ
  for (int idx = tid; idx < 484; idx += 256) {
    int iy = idx / 22, ix = idx % 22;
    int yy = y0 + iy - PADK, xx = x0 + ix - PADK;
    bool ok = (yy >= 0 && yy < HH && xx >= 0 && xx < WW);
    if (FIRST) {
      // fused depth_latent: 3x3 conv over ld (zero-padded already)
#pragma unroll
      for (int c = 0; c < CPG; ++c) {
        float a = b_dp[c0 + c];
#pragma unroll
        for (int dy = 0; dy < 3; ++dy)
#pragma unroll
          for (int dx = 0; dx < 3; ++dx)
            a = fmaf(w_dp[(c0 + c) * 9 + dy * 3 + dx],
                     ld[(iy + dy) * 24 + (ix + dx)], a);
        ls[c * 22 * LSTR + iy * LSTR + ix] = ok ? a : 0.f;
      }
    } else {
      float s = ok ? invZ[b * HWSZ + yy * WW + xx] : 0.f;
#pragma unroll
      for (int c = 0; c < CPG; ++c)
        ls[c * 22 * LSTR + iy * LSTR + ix] =
            ok ? src[((size_t)b * CC + c0 + c) * HWSZ + yy * WW + xx] * s : 0.f;
    }
  }
  __syncthreads();

  // per-thread 3x3x3 texture patch in registers
  float patch[27];
#pragma unroll
  for (int ci = 0; ci < 3; ++ci)
#pragma unroll
    for (int dy = 0; dy < 3; ++dy)
#pragma unroll
      for (int dx = 0; dx < 3; ++dx)
        patch[ci * 9 + dy * 3 + dx] = lt[ci * 324 + (ty + dy) * 18 + (tx + dx)];

  int p = (y0 + ty) * WW + (x0 + tx);
  float z = 0.f, res = 0.f;
  const float* lsbase = ls + ty * LSTR + tx;
#pragma unroll 1   // keep channel loop rolled: caps I$ at ~1 channel body
  for (int c = 0; c < CPG; ++c) {
    int cg = c0 + c;
    const float* wrow = w_kp + (size_t)cg * KK * 27;  // uniform -> s_load/K$
    const float* brow = b_kp + (size_t)cg * KK;
    const float* lsc = lsbase + c * 22 * LSTR;
    float accc = 0.f;
#pragma unroll
    for (int i = 0; i < KSZ; ++i)
#pragma unroll
      for (int j = 0; j < KSZ; ++j) {
        const int kk = i * KSZ + j;
        float logit = brow[kk];
        const float* w = wrow + kk * 27;
#pragma unroll
        for (int m = 0; m < 27; ++m) logit = fmaf(w[m], patch[m], logit);
        float e = __expf(logit);
        if (FIRST) z += e;
        accc = fmaf(e, lsc[i * LSTR + j], accc);
      }
    if (FINAL) res = fmaf(w_td[cg], accc, res);
    else dst[((size_t)b * CC + cg) * HWSZ + p] = accc;
  }
  if (FIRST) part[(size_t)g * BB * HWSZ + b * HWSZ + p] = z;
  if (FINAL) part[(size_t)g * BB * HWSZ + b * HWSZ + p] = res;
}

// invZ = 1 / sum_g zpart  (z is iteration-invariant: computed once)
__global__ __launch_bounds__(256) void k_zred(const float* __restrict__ zpart,
                                              float* __restrict__ invZ) {
  int t = blockIdx.x * 256 + threadIdx.x;  // 0 .. B*HW-1
  float z = 0.f;
#pragma unroll
  for (int g = 0; g < G; ++g) z += zpart[(size_t)g * BB * HWSZ + t];
  invZ[t] = 1.f / z;
}

// out = (sum_g respart) * invZ + b_td
__global__ __launch_bounds__(256) void k_final(const float* __restrict__ respart,
                                               const float* __restrict__ invZ,
                                               const float* __restrict__ b_td,
                                               float* __restrict__ out) {
  int t = blockIdx.x * 256 + threadIdx.x;
  float r = 0.f;
#pragma unroll
  for (int g = 0; g < G; ++g) r += respart[(size_t)g * BB * HWSZ + t];
  out[t] = fmaf(r, invZ[t], b_td[0]);
}

// ---------------------------------------------------------------------------
extern "C" void kernel_launch(void* const* d_in, const int* in_sizes, int n_in,
                              void* d_out, int out_size, void* d_ws, size_t ws_size,
                              hipStream_t stream) {
  const float* depth = (const float*)d_in[0];
  const float* tex   = (const float*)d_in[1];
  const float* w_dp  = (const float*)d_in[2];
  const float* b_dp  = (const float*)d_in[3];
  const float* w_kp  = (const float*)d_in[4];
  const float* b_kp  = (const float*)d_in[5];
  const float* w_td  = (const float*)d_in[6];
  const float* b_td  = (const float*)d_in[7];
  float* out = (float*)d_out;

  // workspace: 2 x 12.58 MB ping-pong + 4 MB partials + 0.5 MB invZ = ~29.7 MB
  char* ws = (char*)d_ws;
  const size_t buf_elems = (size_t)BB * CC * HWSZ;
  float* bufA = (float*)ws;
  float* bufB = (float*)(ws + buf_elems * 4);
  float* part = (float*)(ws + 2 * buf_elems * 4);                       // [G][B][HW]
  float* invZ = (float*)(ws + 2 * buf_elems * 4 +
                         (size_t)G * BB * HWSZ * 4);

  dim3 grid(WW / 16, HH / 16, BB * G), blk(16, 16);
  dim3 grid1(BB * HWSZ / 256), blk1(256);

  // iter1: fused depth_latent staging; outputs unnormalized acc + partial z
  k_diffuse_g<true, false><<<grid, blk, 0, stream>>>(
      depth, nullptr, nullptr, tex, w_dp, b_dp, w_kp, b_kp, bufB, part, w_td);
  k_zred<<<grid1, blk1, 0, stream>>>(part, invZ);
  // iter2, iter3: unnormalized ping-pong, invZ folded into staging
  k_diffuse_g<false, false><<<grid, blk, 0, stream>>>(
      depth, bufB, invZ, tex, w_dp, b_dp, w_kp, b_kp, bufA, part, w_td);
  k_diffuse_g<false, false><<<grid, blk, 0, stream>>>(
      depth, bufA, invZ, tex, w_dp, b_dp, w_kp, b_kp, bufB, part, w_td);
  // iter4: fused to_depth partials per group
  k_diffuse_g<false, true><<<grid, blk, 0, stream>>>(
      depth, bufB, invZ, tex, w_dp, b_dp, w_kp, b_kp, nullptr, part, w_td);
  k_final<<<grid1, blk1, 0, stream>>>(part, invZ, b_td, out);
}